// Round 7
// baseline (441.751 us; speedup 1.0000x reference)
//
#include <hip/hip_runtime.h>

// Problem constants: B=16384, D_in=512, H=512
#define M_ROWS 16384
#define N_COLS 1536   // 3*H
#define K_DIM  512
#define H_DIM  512

typedef __attribute__((ext_vector_type(8))) short short8;   // 8 bf16 = 4 VGPRs
typedef __attribute__((ext_vector_type(16))) float f32x16;  // 32x32 MFMA acc

__device__ __forceinline__ unsigned short f2bf(float f) {
  unsigned u = __float_as_uint(f);
  u += 0x7fffu + ((u >> 16) & 1u);   // RNE
  return (unsigned short)(u >> 16);
}
__device__ __forceinline__ float bf2f(unsigned short h) {
  return __uint_as_float(((unsigned)h) << 16);
}

__device__ __forceinline__ void gload_lds16(const void* g, void* l) {
  __builtin_amdgcn_global_load_lds((const __attribute__((address_space(1))) void*)g,
                                   (__attribute__((address_space(3))) void*)l,
                                   16, 0, 0);
}

// ---------------- fp32 -> bf16 convert, all 4 buffers; also zeroes tickets ---
__global__ __launch_bounds__(256) void cvt_all(
    const float* __restrict__ x, const float* __restrict__ hx,
    const float* __restrict__ Wi, const float* __restrict__ Wh,
    unsigned short* __restrict__ xb, unsigned short* __restrict__ hxb,
    unsigned short* __restrict__ Wib, unsigned short* __restrict__ Whb,
    int* __restrict__ cnt) {
  int i = blockIdx.x * blockDim.x + threadIdx.x;   // grid exactly 4587520 threads
  if (blockIdx.x == 0 && threadIdx.x < 128) cnt[threadIdx.x] = 0;  // ticket reset
  const float* s; unsigned short* d; int off;
  if (i < 2097152)      { s = x;  d = xb;  off = i; }
  else if (i < 4194304) { s = hx; d = hxb; off = i - 2097152; }
  else if (i < 4390912) { s = Wi; d = Wib; off = i - 4194304; }
  else                  { s = Wh; d = Whb; off = i - 4390912; }
  float4 f = ((const float4*)s)[off];
  ushort4 u;
  u.x = f2bf(f.x); u.y = f2bf(f.y); u.z = f2bf(f.z); u.w = f2bf(f.w);
  ((ushort4*)d)[off] = u;
}

// ---------------- GEMM + ticketed finalize, one dispatch ---------------------
// Block bid: mp = bid/6 (m-panel, 128 rows), rem = bid%6: mat = rem&1,
// ng = rem>>1 -> computes n-tiles ng*4..ng*4+3 of matrix `mat` with r0's proven
// tile body (128x128, BK=64, 4 waves 2x2, XOR swizzle c^(r&7), permuted store).
// After its 4 tiles: __threadfence + atomicAdd(&cnt[mp]); the 6th arriver (all
// 24 tiles of rows mp*128.. done, fences passed) finalizes those 128 rows.
// No spinning -> correct under any dispatch order / residency (G16).
__global__ __launch_bounds__(256, 4) void gemm_fin(
    const unsigned short* __restrict__ xb, const unsigned short* __restrict__ hxb,
    const unsigned short* __restrict__ Wib, const unsigned short* __restrict__ Whb,
    const float* __restrict__ b_i2h, const float* __restrict__ b_h2h,
    unsigned short* __restrict__ xt, unsigned short* __restrict__ ht,
    float* __restrict__ out, int* __restrict__ cnt) {
  const int bid = blockIdx.x;
  const int mp  = bid / 6;
  const int rem = bid % 6;
  const int mat = rem & 1;
  const int ng  = rem >> 1;
  const int m0  = mp * 128;

  const unsigned short* A  = mat ? hxb : xb;
  const unsigned short* Bw = mat ? Whb : Wib;
  const float* bias        = mat ? b_h2h : b_i2h;
  unsigned short* outp     = mat ? ht : xt;

  __shared__ short lds[2 * 128 * 64];  // A tile then B tile, 32 KiB
  short* ldsA = lds;
  short* ldsB = lds + 128 * 64;
  __shared__ int dofin;

  const int t = threadIdx.x;
  const int w = t >> 6, lane = t & 63;
  const int w_row = w >> 1, w_col = w & 1;
  const int l31 = lane & 31, h = lane >> 5;
  const int srow = lane >> 3;                       // 0..7 row within 8-row seg
  const int scol = ((lane & 7) ^ srow) * 8;         // XOR-swizzled source chunk

  for (int nt = 0; nt < 4; ++nt) {
    const int n0 = (ng * 4 + nt) * 128;

    f32x16 acc[2][2];
#pragma unroll
    for (int i = 0; i < 2; ++i)
#pragma unroll
      for (int j = 0; j < 2; ++j)
#pragma unroll
        for (int r = 0; r < 16; ++r) acc[i][j][r] = 0.f;

    for (int k0 = 0; k0 < K_DIM; k0 += 64) {
#pragma unroll
      for (int q = 0; q < 4; ++q) {
        const int base_row = w * 32 + q * 8;
        gload_lds16(A  + (size_t)(m0 + base_row + srow) * K_DIM + k0 + scol,
                    &ldsA[base_row * 64]);
        gload_lds16(Bw + (size_t)(n0 + base_row + srow) * K_DIM + k0 + scol,
                    &ldsB[base_row * 64]);
      }
      __syncthreads();
#pragma unroll
      for (int kk = 0; kk < 4; ++kk) {
        // lane needs A[m=l31][k = kk*16 + h*8 + j] -> logical chunk kk*2+h,
        // physical chunk (kk*2+h) ^ (l31&7)
        const int chunk = ((kk * 2 + h) ^ (l31 & 7)) * 8;
        short8 af[2], bfr[2];
#pragma unroll
        for (int i = 0; i < 2; ++i)
          af[i] = *(const short8*)&ldsA[(w_row * 64 + i * 32 + l31) * 64 + chunk];
#pragma unroll
        for (int j = 0; j < 2; ++j)
          bfr[j] = *(const short8*)&ldsB[(w_col * 64 + j * 32 + l31) * 64 + chunk];
#pragma unroll
        for (int i = 0; i < 2; ++i)
#pragma unroll
          for (int j = 0; j < 2; ++j)
            acc[i][j] = __builtin_amdgcn_mfma_f32_32x32x16_bf16(af[i], bfr[j], acc[i][j], 0, 0, 0);
      }
      __syncthreads();
    }

    // Epilogue: bias + packed permuted ushort2 store.
    // C/D: col=l31, row=(reg&3)+8*(reg>>2)+4*h.  Permuted slot within each
    // 64-group: value for true col 32*j+c stored at slot 2c+j.
    const float biasj0 = bias[n0 + w_col * 64 + l31];
    const float biasj1 = bias[n0 + w_col * 64 + 32 + l31];
#pragma unroll
    for (int i = 0; i < 2; ++i) {
#pragma unroll
      for (int g = 0; g < 4; ++g) {
#pragma unroll
        for (int d = 0; d < 4; ++d) {
          const int reg = g * 4 + d;
          const int row = d + 8 * g + 4 * h;
          ushort2 pk;
          pk.x = f2bf(acc[i][0][reg] + biasj0);
          pk.y = f2bf(acc[i][1][reg] + biasj1);
          *(ushort2*)(outp + (size_t)(m0 + w_row * 64 + i * 32 + row) * N_COLS +
                      n0 + w_col * 64 + 2 * l31) = pk;
        }
      }
    }
  }

  // ---- ticket: 6th arriver for this m-panel finalizes its 128 rows ----------
  __syncthreads();                      // all waves' stores complete (vmcnt 0)
  if (t == 0) {
    __threadfence();                    // release: publish xt/ht stores
    dofin = (atomicAdd(&cnt[mp], 1) == 5);
  }
  __syncthreads();
  if (!dofin) return;
  __threadfence();                      // acquire: see other blocks' stores

  // ---- finalize: wave w handles rows m0 + w*32 .. +31 (r0 body per row) -----
  // Permuted slot s (within aligned 64-group) holds true col 32*(s&1)+(s>>1).
  // Lane l reads slots 8l..8l+7 per 512-section: elem e -> true col
  // base4 + 32*(e&1) + (e>>1), base4 = 64*(l>>3)+4*(l&7).
  const int base4 = 64 * (lane >> 3) + 4 * (lane & 7);
  for (int r = 0; r < 32; ++r) {
    const int b = m0 + w * 32 + r;
    const size_t rb = (size_t)b * N_COLS;

    const short8 sxr = *(const short8*)&xt[rb + 8 * lane];
    const short8 sxz = *(const short8*)&xt[rb + 512 + 8 * lane];
    const short8 sxn = *(const short8*)&xt[rb + 1024 + 8 * lane];
    const short8 shr = *(const short8*)&ht[rb + 8 * lane];
    const short8 shz = *(const short8*)&ht[rb + 512 + 8 * lane];
    const short8 shn = *(const short8*)&ht[rb + 1024 + 8 * lane];
    const unsigned short* hxrow = hxb + (size_t)b * H_DIM;
    const ushort4 hx0u = *(const ushort4*)&hxrow[base4];
    const ushort4 hx1u = *(const ushort4*)&hxrow[base4 + 32];

    float pr[8] = {0.f, 0.f, 0.f, 0.f, 0.f, 0.f, 0.f, 0.f};
#pragma unroll
    for (int k = 0; k < 8; ++k) {
      const float xr = bf2f((unsigned short)sxr[k]);
      const float xz = bf2f((unsigned short)sxz[k]);
      const float xn = bf2f((unsigned short)sxn[k]);
      const float hr = bf2f((unsigned short)shr[k]);
      const float hz = bf2f((unsigned short)shz[k]);
      const float hn = bf2f((unsigned short)shn[k]);
      pr[0] += xr + xz;
      pr[1] += xr * xr + xz * xz;
      pr[2] += xn;
      pr[3] += xn * xn;
      pr[4] += hr + hz;
      pr[5] += hr * hr + hz * hz;
      pr[6] += hn;
      pr[7] += hn * hn;
    }
#pragma unroll
    for (int msk = 1; msk < 64; msk <<= 1)
#pragma unroll
      for (int k = 0; k < 8; ++k) pr[k] += __shfl_xor(pr[k], msk);

    const float inv2H = 1.f / 1024.f, invH = 1.f / 512.f;
    const float mx0 = pr[0] * inv2H;
    const float ix0 = rsqrtf(pr[1] * inv2H - mx0 * mx0 + 1e-5f);
    const float mx1 = pr[2] * invH;
    const float ix1 = rsqrtf(pr[3] * invH - mx1 * mx1 + 1e-5f);
    const float mh0 = pr[4] * inv2H;
    const float ih0 = rsqrtf(pr[5] * inv2H - mh0 * mh0 + 1e-5f);
    const float mh1 = pr[6] * invH;
    const float ih1 = rsqrtf(pr[7] * invH - mh1 * mh1 + 1e-5f);

    auto calc = [&](float xrv, float xzv, float xnv, float hrv, float hzv,
                    float hnv, float hxs) -> float {
      float ar = (xrv - mx0) * ix0 + (hrv - mh0) * ih0;
      float az = (xzv - mx0) * ix0 + (hzv - mh0) * ih0;
      float rr = 1.f / (1.f + __expf(-ar));
      float zz = 1.f / (1.f + __expf(-az));
      float arg = (xnv - mx1) * ix1 + rr * ((hnv - mh1) * ih1);
      float e2 = __expf(2.f * arg);
      float nn = (e2 - 1.f) / (e2 + 1.f);
      return zz * hxs + (1.f - zz) * nn;
    };

    float* orow = out + (size_t)b * H_DIM;
    float4 r0, r1;
    float* r0p = (float*)&r0;
    float* r1p = (float*)&r1;
    const unsigned short hx0a[4] = {hx0u.x, hx0u.y, hx0u.z, hx0u.w};
    const unsigned short hx1a[4] = {hx1u.x, hx1u.y, hx1u.z, hx1u.w};
#pragma unroll
    for (int k = 0; k < 4; ++k) {
      r0p[k] = calc(bf2f((unsigned short)sxr[2 * k]), bf2f((unsigned short)sxz[2 * k]),
                    bf2f((unsigned short)sxn[2 * k]), bf2f((unsigned short)shr[2 * k]),
                    bf2f((unsigned short)shz[2 * k]), bf2f((unsigned short)shn[2 * k]),
                    bf2f(hx0a[k]));
      r1p[k] = calc(bf2f((unsigned short)sxr[2 * k + 1]), bf2f((unsigned short)sxz[2 * k + 1]),
                    bf2f((unsigned short)sxn[2 * k + 1]), bf2f((unsigned short)shr[2 * k + 1]),
                    bf2f((unsigned short)shz[2 * k + 1]), bf2f((unsigned short)shn[2 * k + 1]),
                    bf2f(hx1a[k]));
    }
    *(float4*)&orow[base4] = r0;
    *(float4*)&orow[base4 + 32] = r1;
  }
}

// ---------------- launch ----------------
// Workspace layout (bytes):            offset        size
//   xb  (bf16 x,  16384x512)               0      16777216
//   hxb (bf16 hx, 16384x512)        16777216      16777216
//   Wib (bf16,  1536x512)           33554432       1572864
//   Whb (bf16,  1536x512)           35127296       1572864
//   xt  (bf16, 16384x1536, permuted) 36700160     50331648
//   ht  (bf16, 16384x1536, permuted) 87031808     50331648
//   cnt (int, 128 m-panel tickets)  137363456           512
extern "C" void kernel_launch(void* const* d_in, const int* in_sizes, int n_in,
                              void* d_out, int out_size, void* d_ws, size_t ws_size,
                              hipStream_t stream) {
  const float* x  = (const float*)d_in[0];
  const float* hx = (const float*)d_in[1];
  const float* Wi = (const float*)d_in[2];
  const float* bi = (const float*)d_in[3];
  const float* Wh = (const float*)d_in[4];
  const float* bh = (const float*)d_in[5];
  float* out = (float*)d_out;

  char* ws = (char*)d_ws;
  unsigned short* xb  = (unsigned short*)(ws);
  unsigned short* hxb = (unsigned short*)(ws + 16777216);
  unsigned short* Wib = (unsigned short*)(ws + 33554432);
  unsigned short* Whb = (unsigned short*)(ws + 35127296);
  unsigned short* xt  = (unsigned short*)(ws + 36700160);
  unsigned short* ht  = (unsigned short*)(ws + 87031808);
  int* cnt            = (int*)(ws + 137363456);

  cvt_all<<<17920, 256, 0, stream>>>(x, hx, Wi, Wh, xb, hxb, Wib, Whb, cnt);

  gemm_fin<<<768, 256, 0, stream>>>(xb, hxb, Wib, Whb, bi, bh, xt, ht, out, cnt);
}

// Round 8
// 207.961 us; speedup vs baseline: 2.1242x; 2.1242x over previous
//
#include <hip/hip_runtime.h>

// Problem constants: B=16384, D_in=512, H=512
#define M_ROWS 16384
#define N_COLS 1536   // 3*H
#define K_DIM  512
#define H_DIM  512

typedef __attribute__((ext_vector_type(8))) short short8;   // 8 bf16 = 4 VGPRs
typedef __attribute__((ext_vector_type(16))) float f32x16;  // 32x32 MFMA acc

__device__ __forceinline__ unsigned short f2bf(float f) {
  unsigned u = __float_as_uint(f);
  u += 0x7fffu + ((u >> 16) & 1u);   // RNE
  return (unsigned short)(u >> 16);
}
__device__ __forceinline__ float bf2f(unsigned short h) {
  return __uint_as_float(((unsigned)h) << 16);
}

__device__ __forceinline__ void gload_lds16(const void* g, void* l) {
  __builtin_amdgcn_global_load_lds((const __attribute__((address_space(1))) void*)g,
                                   (__attribute__((address_space(3))) void*)l,
                                   16, 0, 0);
}

// ---------------- fp32 -> bf16 convert, all 4 buffers (r5-identical) --------
__global__ __launch_bounds__(256) void cvt_all(
    const float* __restrict__ x, const float* __restrict__ hx,
    const float* __restrict__ Wi, const float* __restrict__ Wh,
    unsigned short* __restrict__ xb, unsigned short* __restrict__ hxb,
    unsigned short* __restrict__ Wib, unsigned short* __restrict__ Whb) {
  int i = blockIdx.x * blockDim.x + threadIdx.x;   // grid exactly 4587520 threads
  const float* s; unsigned short* d; int off;
  if (i < 2097152)      { s = x;  d = xb;  off = i; }
  else if (i < 4194304) { s = hx; d = hxb; off = i - 2097152; }
  else if (i < 4390912) { s = Wi; d = Wib; off = i - 4194304; }
  else                  { s = Wh; d = Whb; off = i - 4390912; }
  float4 f = ((const float4*)s)[off];
  ushort4 u;
  u.x = f2bf(f.x); u.y = f2bf(f.y); u.z = f2bf(f.z); u.w = f2bf(f.w);
  ((ushort4*)d)[off] = u;
}

// ---------------- GEMM: 256x256 tile, 8 waves, 4-phase/K-tile pipeline ------
// C[m][n] = sum_k A[m][k]*W[n][k] + bias[n].  blockIdx.z: 0=(x,Wi,bi,xt) 1=(hx,Wh,bh,ht)
// m201-style schedule: BK=64, dbuf LDS (A 2x[256][64], B 2x[256][64] = 128 KiB),
// phase = block-C-quadrant (Qm,Qn); waves arranged 2x4 inside a quadrant so each
// wave's per-phase subtile is 64x32 (2x1 frags of 32x32x16, 4 k-steps = 8 MFMA).
// Per phase: {ds_read frags | stage ONE half-tile (2 gload_lds/thread) |
//             s_waitcnt vmcnt(8) | s_barrier | setprio(1) 8xMFMA setprio(0) | s_barrier}.
// Stage schedule (phase kt.q): q0->B-h1(kt+1), q1->A-h1(kt+1), q2->A-h0(kt+2),
// q3->B-h0(kt+2); every overwrite lands >=1 barrier after the slot's last read
// (A-h0 read q0, B-h0 read q0/q2[reg-cached], B-h1 q1/q3, A-h1 q2).  Tail phases
// stage dummies into scratch so the per-phase load count is invariant -> uniform
// vmcnt(8) everywhere (each half lands exactly by its first read; ~5 phases of
// flight).  Frag reads: A reloaded q0/q2, B reg-cached (bf0 q0, bf1 q1).
// LDS XOR swizzle: 16B chunk c of row r at physical chunk c^(r&7) (r0-identical).
// Store permutation (NEW): within each aligned 256-col group, value for true col
// 128*Qn + c (c=(w&3)*32+l31) stored at slot 2c+Qn, i.e. true = 128*(s&1)+(s>>1).
__global__ __launch_bounds__(512, 2) void gemm_bf16(
    const unsigned short* __restrict__ xb, const unsigned short* __restrict__ hxb,
    const unsigned short* __restrict__ Wib, const unsigned short* __restrict__ Whb,
    const float* __restrict__ b_i2h, const float* __restrict__ b_h2h,
    unsigned short* __restrict__ xt, unsigned short* __restrict__ ht) {
  const int mat = blockIdx.z;
  const unsigned short* A  = mat ? hxb : xb;
  const unsigned short* Bw = mat ? Whb : Wib;
  const float* bias        = mat ? b_h2h : b_i2h;
  unsigned short* outp     = mat ? ht : xt;

  const int m0 = blockIdx.x * 256;
  const int n0 = blockIdx.y * 256;

  // A dbuf: [2][256][64] @0 ; B dbuf: [2][256][64] @32768 ; scratch @65536 (8 KB)
  __shared__ short lds[69632];   // 139,264 B

  const int t = threadIdx.x;
  const int w = t >> 6, lane = t & 63;
  const int wr = w >> 2;         // 0..1 row-group inside quadrant
  const int wc = w & 3;          // 0..3 col-group inside quadrant
  const int l31 = lane & 31, h = lane >> 5;
  const int srow = lane >> 3;                   // 0..7 row within 8-row seg
  const int scol = ((lane & 7) ^ srow) * 8;     // XOR-swizzled source chunk

  auto stA = [&](int T, int hh) {   // stage A half hh of K-tile T (2 loads/thread)
    if (T < 8) {
      short* dst = &lds[(T & 1) * 16384 + hh * 8192];
      const unsigned short* sp =
          A + (size_t)(m0 + hh * 128 + w * 8 + srow) * K_DIM + T * 64 + scol;
      gload_lds16(sp, &dst[(w * 8) * 64]);
      gload_lds16(sp + (size_t)64 * K_DIM, &dst[(64 + w * 8) * 64]);
    } else {  // dummy: keep per-phase vmcnt count invariant
      gload_lds16(A + (size_t)srow * K_DIM + scol, &lds[65536 + w * 512]);
      gload_lds16(A + (size_t)srow * K_DIM + scol, &lds[65536 + w * 512]);
    }
  };
  auto stB = [&](int T, int hh) {
    if (T < 8) {
      short* dst = &lds[32768 + (T & 1) * 16384 + hh * 8192];
      const unsigned short* sp =
          Bw + (size_t)(n0 + hh * 128 + w * 8 + srow) * K_DIM + T * 64 + scol;
      gload_lds16(sp, &dst[(w * 8) * 64]);
      gload_lds16(sp + (size_t)64 * K_DIM, &dst[(64 + w * 8) * 64]);
    } else {
      gload_lds16(Bw + (size_t)srow * K_DIM + scol, &lds[65536 + w * 512]);
      gload_lds16(Bw + (size_t)srow * K_DIM + scol, &lds[65536 + w * 512]);
    }
  };

  f32x16 acc[2][2][2];   // [Qm][Qn][i2]
#pragma unroll
  for (int a = 0; a < 2; ++a)
#pragma unroll
    for (int b = 0; b < 2; ++b)
#pragma unroll
      for (int c = 0; c < 2; ++c)
#pragma unroll
        for (int r = 0; r < 16; ++r) acc[a][b][c][r] = 0.f;

  // Prologue: kt0 fully (A-h0,B-h0,B-h1,A-h1) + kt1 partial (A-h0,B-h0) = 12 loads.
  stA(0, 0); stB(0, 0); stB(0, 1); stA(0, 1); stA(1, 0); stB(1, 0);
  asm volatile("s_waitcnt vmcnt(8)" ::: "memory");   // A-h0(0), B-h0(0) landed
  __builtin_amdgcn_s_barrier();
  asm volatile("" ::: "memory");

  // frag chunk offsets: k-chunk kk*2+h, physical ^= (row&7) == (l31&7)
  int ch[4];
#pragma unroll
  for (int kk = 0; kk < 4; ++kk) ch[kk] = ((kk * 2 + h) ^ (l31 & 7)) * 8;

#pragma unroll 1
  for (int kt = 0; kt < 8; ++kt) {
    const short* lA = &lds[(kt & 1) * 16384];
    const short* lB = &lds[32768 + (kt & 1) * 16384];
    short8 af[2][4], bf0[4], bf1[4];

    // ======== phase q=0 : quadrant (Qm=0, Qn=0) ========
#pragma unroll
    for (int i2 = 0; i2 < 2; ++i2)
#pragma unroll
      for (int kk = 0; kk < 4; ++kk)
        af[i2][kk] = *(const short8*)&lA[(wr * 64 + i2 * 32 + l31) * 64 + ch[kk]];
#pragma unroll
    for (int kk = 0; kk < 4; ++kk)
      bf0[kk] = *(const short8*)&lB[(wc * 32 + l31) * 64 + ch[kk]];
    stB(kt + 1, 1);
    asm volatile("s_waitcnt vmcnt(8)" ::: "memory");
    __builtin_amdgcn_s_barrier();
    asm volatile("" ::: "memory");
    __builtin_amdgcn_s_setprio(1);
#pragma unroll
    for (int i2 = 0; i2 < 2; ++i2)
#pragma unroll
      for (int kk = 0; kk < 4; ++kk)
        acc[0][0][i2] = __builtin_amdgcn_mfma_f32_32x32x16_bf16(af[i2][kk], bf0[kk], acc[0][0][i2], 0, 0, 0);
    __builtin_amdgcn_s_setprio(0);
    asm volatile("" ::: "memory");
    __builtin_amdgcn_s_barrier();
    asm volatile("" ::: "memory");

    // ======== phase q=1 : quadrant (Qm=0, Qn=1) ========
#pragma unroll
    for (int kk = 0; kk < 4; ++kk)
      bf1[kk] = *(const short8*)&lB[(128 + wc * 32 + l31) * 64 + ch[kk]];
    stA(kt + 1, 1);
    asm volatile("s_waitcnt vmcnt(8)" ::: "memory");
    __builtin_amdgcn_s_barrier();
    asm volatile("" ::: "memory");
    __builtin_amdgcn_s_setprio(1);
#pragma unroll
    for (int i2 = 0; i2 < 2; ++i2)
#pragma unroll
      for (int kk = 0; kk < 4; ++kk)
        acc[0][1][i2] = __builtin_amdgcn_mfma_f32_32x32x16_bf16(af[i2][kk], bf1[kk], acc[0][1][i2], 0, 0, 0);
    __builtin_amdgcn_s_setprio(0);
    asm volatile("" ::: "memory");
    __builtin_amdgcn_s_barrier();
    asm volatile("" ::: "memory");

    // ======== phase q=2 : quadrant (Qm=1, Qn=0) ========
#pragma unroll
    for (int i2 = 0; i2 < 2; ++i2)
#pragma unroll
      for (int kk = 0; kk < 4; ++kk)
        af[i2][kk] = *(const short8*)&lA[(128 + wr * 64 + i2 * 32 + l31) * 64 + ch[kk]];
    stA(kt + 2, 0);
    asm volatile("s_waitcnt vmcnt(8)" ::: "memory");
    __builtin_amdgcn_s_barrier();
    asm volatile("" ::: "memory");
    __builtin_amdgcn_s_setprio(1);
#pragma unroll
    for (int i2 = 0; i2 < 2; ++i2)
#pragma unroll
      for (int kk = 0; kk < 4; ++kk)
        acc[1][0][i2] = __builtin_amdgcn_mfma_f32_32x32x16_bf16(af[i2][kk], bf0[kk], acc[1][0][i2], 0, 0, 0);
    __builtin_amdgcn_s_setprio(0);
    asm volatile("" ::: "memory");
    __builtin_amdgcn_s_barrier();
    asm volatile("" ::: "memory");

    // ======== phase q=3 : quadrant (Qm=1, Qn=1) ========
    stB(kt + 2, 0);
    asm volatile("s_waitcnt vmcnt(8)" ::: "memory");
    __builtin_amdgcn_s_barrier();
    asm volatile("" ::: "memory");
    __builtin_amdgcn_s_setprio(1);
#pragma unroll
    for (int i2 = 0; i2 < 2; ++i2)
#pragma unroll
      for (int kk = 0; kk < 4; ++kk)
        acc[1][1][i2] = __builtin_amdgcn_mfma_f32_32x32x16_bf16(af[i2][kk], bf1[kk], acc[1][1][i2], 0, 0, 0);
    __builtin_amdgcn_s_setprio(0);
    asm volatile("" ::: "memory");
    __builtin_amdgcn_s_barrier();
    asm volatile("" ::: "memory");
  }

  // Epilogue: bias + packed permuted ushort2 store.
  // C/D frag: col=l31, row=(reg&3)+8*(reg>>2)+4*h.  True col = n0 + 128*Qn + cQ,
  // cQ = wc*32+l31; stored at linear slot n0 + 2*cQ + Qn.
  const int cQ = wc * 32 + l31;
  const float bias0 = bias[n0 + cQ];
  const float bias1 = bias[n0 + 128 + cQ];
#pragma unroll
  for (int Qm = 0; Qm < 2; ++Qm) {
#pragma unroll
    for (int i2 = 0; i2 < 2; ++i2) {
#pragma unroll
      for (int g = 0; g < 4; ++g) {
#pragma unroll
        for (int d = 0; d < 4; ++d) {
          const int reg = g * 4 + d;
          const int row = m0 + Qm * 128 + wr * 64 + i2 * 32 + (d + 8 * g + 4 * h);
          ushort2 pk;
          pk.x = f2bf(acc[Qm][0][i2][reg] + bias0);
          pk.y = f2bf(acc[Qm][1][i2][reg] + bias1);
          *(ushort2*)(outp + (size_t)row * N_COLS + n0 + 2 * cQ) = pk;
        }
      }
    }
  }
}

// ---------------- finalize: wave-per-row (decode updated for new permutation) -
// Within each aligned 256-col group, slot s holds true col 128*(s&1)+(s>>1).
// Lane l reads slots 8l..8l+7 per 512-section: group g=l>>5, elem e -> true col
// base8 + 128*(e&1) + (e>>1), base8 = 256*(l>>5) + 4*(l&31).
__global__ __launch_bounds__(256, 6) void finalize_kernel(
    const unsigned short* __restrict__ xt, const unsigned short* __restrict__ ht,
    const unsigned short* __restrict__ hxb, float* __restrict__ out) {
  const int w = threadIdx.x >> 6, lane = threadIdx.x & 63;
  const int b = blockIdx.x * 4 + w;            // one row per wave
  const size_t rb = (size_t)b * N_COLS;

  const short8 sxr = *(const short8*)&xt[rb + 8 * lane];
  const short8 sxz = *(const short8*)&xt[rb + 512 + 8 * lane];
  const short8 sxn = *(const short8*)&xt[rb + 1024 + 8 * lane];
  const short8 shr = *(const short8*)&ht[rb + 8 * lane];
  const short8 shz = *(const short8*)&ht[rb + 512 + 8 * lane];
  const short8 shn = *(const short8*)&ht[rb + 1024 + 8 * lane];
  const int base8 = 256 * (lane >> 5) + 4 * (lane & 31);
  const unsigned short* hxrow = hxb + (size_t)b * H_DIM;
  const ushort4 hx0u = *(const ushort4*)&hxrow[base8];
  const ushort4 hx1u = *(const ushort4*)&hxrow[base8 + 128];

  float pr[8] = {0.f, 0.f, 0.f, 0.f, 0.f, 0.f, 0.f, 0.f};
#pragma unroll
  for (int k = 0; k < 8; ++k) {
    const float xr = bf2f((unsigned short)sxr[k]);
    const float xz = bf2f((unsigned short)sxz[k]);
    const float xn = bf2f((unsigned short)sxn[k]);
    const float hr = bf2f((unsigned short)shr[k]);
    const float hz = bf2f((unsigned short)shz[k]);
    const float hn = bf2f((unsigned short)shn[k]);
    pr[0] += xr + xz;
    pr[1] += xr * xr + xz * xz;
    pr[2] += xn;
    pr[3] += xn * xn;
    pr[4] += hr + hz;
    pr[5] += hr * hr + hz * hz;
    pr[6] += hn;
    pr[7] += hn * hn;
  }
#pragma unroll
  for (int msk = 1; msk < 64; msk <<= 1)
#pragma unroll
    for (int k = 0; k < 8; ++k) pr[k] += __shfl_xor(pr[k], msk);

  const float inv2H = 1.f / 1024.f, invH = 1.f / 512.f;
  const float mx0 = pr[0] * inv2H;
  const float ix0 = rsqrtf(pr[1] * inv2H - mx0 * mx0 + 1e-5f);
  const float mx1 = pr[2] * invH;
  const float ix1 = rsqrtf(pr[3] * invH - mx1 * mx1 + 1e-5f);
  const float mh0 = pr[4] * inv2H;
  const float ih0 = rsqrtf(pr[5] * inv2H - mh0 * mh0 + 1e-5f);
  const float mh1 = pr[6] * invH;
  const float ih1 = rsqrtf(pr[7] * invH - mh1 * mh1 + 1e-5f);

  auto calc = [&](float xrv, float xzv, float xnv, float hrv, float hzv,
                  float hnv, float hxs) -> float {
    float ar = (xrv - mx0) * ix0 + (hrv - mh0) * ih0;
    float az = (xzv - mx0) * ix0 + (hzv - mh0) * ih0;
    float r = 1.f / (1.f + __expf(-ar));
    float z = 1.f / (1.f + __expf(-az));
    float arg = (xnv - mx1) * ix1 + r * ((hnv - mh1) * ih1);
    float e2 = __expf(2.f * arg);
    float nn = (e2 - 1.f) / (e2 + 1.f);
    return z * hxs + (1.f - z) * nn;
  };

  float* orow = out + (size_t)b * H_DIM;
  float4 r0, r1;
  float* r0p = (float*)&r0;
  float* r1p = (float*)&r1;
  const unsigned short hx0a[4] = {hx0u.x, hx0u.y, hx0u.z, hx0u.w};
  const unsigned short hx1a[4] = {hx1u.x, hx1u.y, hx1u.z, hx1u.w};
#pragma unroll
  for (int k = 0; k < 4; ++k) {
    r0p[k] = calc(bf2f((unsigned short)sxr[2 * k]), bf2f((unsigned short)sxz[2 * k]),
                  bf2f((unsigned short)sxn[2 * k]), bf2f((unsigned short)shr[2 * k]),
                  bf2f((unsigned short)shz[2 * k]), bf2f((unsigned short)shn[2 * k]),
                  bf2f(hx0a[k]));
    r1p[k] = calc(bf2f((unsigned short)sxr[2 * k + 1]), bf2f((unsigned short)sxz[2 * k + 1]),
                  bf2f((unsigned short)sxn[2 * k + 1]), bf2f((unsigned short)shr[2 * k + 1]),
                  bf2f((unsigned short)shz[2 * k + 1]), bf2f((unsigned short)shn[2 * k + 1]),
                  bf2f(hx1a[k]));
  }
  *(float4*)&orow[base8] = r0;
  *(float4*)&orow[base8 + 128] = r1;
}

// ---------------- launch ----------------
// Workspace layout (bytes):            offset        size
//   xb  (bf16 x,  16384x512)               0      16777216
//   hxb (bf16 hx, 16384x512)        16777216      16777216
//   Wib (bf16,  1536x512)           33554432       1572864
//   Whb (bf16,  1536x512)           35127296       1572864
//   xt  (bf16, 16384x1536, permuted) 36700160     50331648
//   ht  (bf16, 16384x1536, permuted) 87031808     50331648
extern "C" void kernel_launch(void* const* d_in, const int* in_sizes, int n_in,
                              void* d_out, int out_size, void* d_ws, size_t ws_size,
                              hipStream_t stream) {
  const float* x  = (const float*)d_in[0];
  const float* hx = (const float*)d_in[1];
  const float* Wi = (const float*)d_in[2];
  const float* bi = (const float*)d_in[3];
  const float* Wh = (const float*)d_in[4];
  const float* bh = (const float*)d_in[5];
  float* out = (float*)d_out;

  char* ws = (char*)d_ws;
  unsigned short* xb  = (unsigned short*)(ws);
  unsigned short* hxb = (unsigned short*)(ws + 16777216);
  unsigned short* Wib = (unsigned short*)(ws + 33554432);
  unsigned short* Whb = (unsigned short*)(ws + 35127296);
  unsigned short* xt  = (unsigned short*)(ws + 36700160);
  unsigned short* ht  = (unsigned short*)(ws + 87031808);

  cvt_all<<<17920, 256, 0, stream>>>(x, hx, Wi, Wh, xb, hxb, Wib, Whb);

  gemm_bf16<<<dim3(M_ROWS / 256, N_COLS / 256, 2), 512, 0, stream>>>(
      xb, hxb, Wib, Whb, bi, bh, xt, ht);

  finalize_kernel<<<M_ROWS / 4, 256, 0, stream>>>(xt, ht, hxb, out);
}